// Round 1
// baseline (1032.258 us; speedup 1.0000x reference)
//
#include <hip/hip_runtime.h>
#include <cmath>

#define CC 64
#define HH 512
#define WWID 512
#define HWSZ (HH*WWID)
#define DEPTH 4

// ---------------- init: twiddle tables + transposed local weights ----------------
// ctab[pos*16+k] = cos(2*pi*k*pos/512), stab = sin(...)   (pos<512, k<16)
// ctT[k*512+pos] = same, transposed (for coalesced per-lane reads in combine)
__global__ void k_twiddle(float* __restrict__ ctab, float* __restrict__ stab,
                          float* __restrict__ ctT, float* __restrict__ stT){
  int idx = blockIdx.x*256 + threadIdx.x;     // < 512*16
  int pos = idx >> 4, k = idx & 15;
  int r = (pos * k) & 511;
  double ang = (2.0 * 3.14159265358979323846 / 512.0) * (double)r;
  float c = (float)cos(ang), s = (float)sin(ang);
  ctab[idx] = c;  stab[idx] = s;
  ctT[k*512 + pos] = c;  stT[k*512 + pos] = s;
}

// transpose w_w[d][o][i] -> wwT[d][i][o]
__global__ void k_prep(const float* __restrict__ ww, float* __restrict__ wwT){
  int idx = blockIdx.x*256 + threadIdx.x;     // < 4*64*64
  int d = idx >> 12, r = idx & 4095, o = r >> 6, i = r & 63;
  wwT[(d<<12) + (i<<6) + o] = ww[idx];
}

// ---------------- lift: x[c,h,w] = proj_w[c]*q[h,w] + proj_b[c] ----------------
__global__ void k_lift(const float* __restrict__ q, const float* __restrict__ pw,
                       const float* __restrict__ pb, float* __restrict__ x){
  int idx = blockIdx.x*256 + threadIdx.x;     // < 64*HW
  int c = idx >> 18, p = idx & (HWSZ-1);
  x[idx] = fmaf(pw[c], q[p], pb[c]);
}

// ---------------- A: partial DFT along w: X1[i,h,n] = sum_w x * e^{-2pi i n w/512} ----------------
__global__ __launch_bounds__(256) void k_dftw(const float* __restrict__ x,
                       const float* __restrict__ ctab, const float* __restrict__ stab,
                       float2* __restrict__ X1){
  // block handles 16 rows (row = i*512+h); threads = 16 rows x 16 n
  __shared__ float xs[16][513];               // +1 pad: 4 r-groups land on distinct banks
  int row0 = blockIdx.x * 16;
  for (int idx = threadIdx.x; idx < 16*512; idx += 256){
    int r = idx >> 9, w = idx & 511;
    xs[r][w] = x[(row0 + r)*512 + w];
  }
  __syncthreads();
  int r = threadIdx.x >> 4, n = threadIdx.x & 15;
  float ar = 0.f, ai = 0.f;
  for (int w = 0; w < 512; ++w){
    float xv = xs[r][w];
    ar = fmaf(xv, ctab[w*16 + n], ar);
    ai = fmaf(xv, stab[w*16 + n], ai);
  }
  X1[(row0 + r)*16 + n] = make_float2(ar, -ai);
}

// ---------------- B1: partial DFT along h (chunked): Xfp[ch][i][m*16+n] ----------------
__global__ void k_dfth(const float2* __restrict__ X1, const float* __restrict__ ct,
                       const float* __restrict__ st, float2* __restrict__ Xfp){
  int i = blockIdx.x, ch = blockIdx.y;
  int m = threadIdx.x >> 4, n = threadIdx.x & 15;
  float ar = 0.f, ai = 0.f;
  int h0 = ch * 128;
  for (int hh = 0; hh < 128; ++hh){
    int h = h0 + hh;
    float2 v = X1[(i*512 + h)*16 + n];
    float c = ct[h*16 + m], s = st[h*16 + m];
    // (vx + i vy)(c - i s)
    ar += v.x*c + v.y*s;
    ai += v.y*c - v.x*s;
  }
  Xfp[(ch*64 + i)*256 + threadIdx.x] = make_float2(ar, ai);
}

// ---------------- B2: mode contraction Y[o,m,n] = (1/HW) sum_i Xf[i,m,n]*w[i,o,m,n] ----------------
__global__ void k_contract(const float2* __restrict__ Xfp,
                           const float* __restrict__ wr, const float* __restrict__ wi,
                           float2* __restrict__ Y){
  int o = blockIdx.x, mn = threadIdx.x;
  float ar = 0.f, ai = 0.f;
  for (int j = 0; j < 256; ++j){              // j = ch*64 + i
    int i = j & 63;
    float2 xf = Xfp[j*256 + mn];
    float wrv = wr[(i*64 + o)*256 + mn];
    float wiv = wi[(i*64 + o)*256 + mn];
    ar += xf.x*wrv - xf.y*wiv;
    ai += xf.x*wiv + xf.y*wrv;
  }
  const float sc = 1.f/262144.f;
  Y[o*256 + mn] = make_float2(ar*sc, ai*sc);
}

// ---------------- B3: inverse DFT along h: T[(h*64+o)*16+n] = sum_m Y * e^{+2pi i m h/512} ----------------
__global__ void k_idfth(const float2* __restrict__ Y, const float* __restrict__ ct,
                        const float* __restrict__ st, float2* __restrict__ T){
  int idx = blockIdx.x*256 + threadIdx.x;     // (h*64+o)*16+n
  int n = idx & 15, o = (idx >> 4) & 63, h = idx >> 10;
  float ar = 0.f, ai = 0.f;
  #pragma unroll
  for (int m = 0; m < 16; ++m){
    float2 y = Y[(o*16 + m)*16 + n];
    float c = ct[h*16 + m], s = st[h*16 + m];
    // (yr + i yi)(c + i s)
    ar += y.x*c - y.y*s;
    ai += y.x*s + y.y*c;
  }
  T[idx] = make_float2(ar, ai);
}

// ---------------- C: combine = gelu( iDFT_w(T) + local_conv(x) + b ), in-place ----------------
__global__ __launch_bounds__(256) void k_combine(
    const float* __restrict__ x, const float2* __restrict__ T,
    const float* __restrict__ wwT, const float* __restrict__ wb,
    const float* __restrict__ ctT, const float* __restrict__ stT,
    float* __restrict__ xo)
{
  int h = blockIdx.y;
  int w = blockIdx.x*256 + threadIdx.x;
  float acc[CC];
  #pragma unroll
  for (int o = 0; o < CC; ++o) acc[o] = 0.f;

  // local 1x1 conv: each thread owns one (h,w) column across all channels
  const float* xp = x + h*WWID + w;
  for (int i = 0; i < CC; ++i){
    float xv = xp[i*HWSZ];
    const float* wrow = wwT + i*CC;           // wave-uniform -> scalar loads, contiguous
    #pragma unroll
    for (int o = 0; o < CC; ++o) acc[o] = fmaf(wrow[o], xv, acc[o]);
  }

  // spectral: Re( sum_n T[o,h,n] * e^{+2pi i n w/512} )
  float cv[16], sv[16];
  #pragma unroll
  for (int n = 0; n < 16; ++n){ cv[n] = ctT[n*512 + w]; sv[n] = stT[n*512 + w]; }
  const float2* Tp = T + h*1024;              // [h][o][n], wave-uniform -> scalar loads
  for (int o = 0; o < CC; ++o){
    float sacc = 0.f;
    #pragma unroll
    for (int n = 0; n < 16; ++n){
      float2 t = Tp[o*16 + n];
      sacc = fmaf(t.x, cv[n], sacc);
      sacc = fmaf(-t.y, sv[n], sacc);
    }
    acc[o] += sacc;
  }

  // bias + gelu (jax default: tanh approximation) + in-place store
  #pragma unroll
  for (int o = 0; o < CC; ++o){
    float u = acc[o] + wb[o];
    float z = 0.7978845608028654f * fmaf(0.044715f, u*u*u, u);
    float e = __expf(2.f*z);                  // tanh(z) = 1 - 2/(e+1)
    float g = u - __fdividef(u, e + 1.f);     // = 0.5*u*(1+tanh(z)); inf-safe both tails
    xo[o*HWSZ + h*WWID + w] = g;
  }
}

// ---------------- final projection ----------------
__global__ void k_final(const float* __restrict__ x, const float* __restrict__ fw,
                        const float* __restrict__ fb, float* __restrict__ out){
  int p = blockIdx.x*256 + threadIdx.x;
  float acc = fb[0];
  #pragma unroll
  for (int i = 0; i < CC; ++i) acc = fmaf(fw[i], x[i*HWSZ + p], acc);
  out[p] = acc;
}

extern "C" void kernel_launch(void* const* d_in, const int* in_sizes, int n_in,
                              void* d_out, int out_size, void* d_ws, size_t ws_size,
                              hipStream_t stream) {
  const float* q       = (const float*)d_in[0];
  const float* proj_w  = (const float*)d_in[1];
  const float* proj_b  = (const float*)d_in[2];
  const float* spec_wr = (const float*)d_in[3];
  const float* spec_wi = (const float*)d_in[4];
  const float* w_w     = (const float*)d_in[5];
  const float* w_b     = (const float*)d_in[6];
  const float* final_w = (const float*)d_in[7];
  const float* final_b = (const float*)d_in[8];
  float* out = (float*)d_out;

  char* ws = (char*)d_ws;
  float*  ctab = (float*) (ws + 0);            // 32 KB
  float*  stab = (float*) (ws + 32768);        // 32 KB
  float*  ctT  = (float*) (ws + 65536);        // 32 KB
  float*  stT  = (float*) (ws + 98304);        // 32 KB
  float2* X1   = (float2*)(ws + 131072);       // 4 MB
  float2* Xfp  = (float2*)(ws + 4325376);      // 512 KB
  float2* Y    = (float2*)(ws + 4849664);      // 128 KB
  float2* T    = (float2*)(ws + 4980736);      // 4 MB
  float*  x    = (float*) (ws + 9175040);      // 64 MB
  float*  wwT  = (float*) (ws + 76283904);     // 64 KB  (total ~72.8 MB)

  k_twiddle<<<32, 256, 0, stream>>>(ctab, stab, ctT, stT);
  k_prep<<<64, 256, 0, stream>>>(w_w, wwT);
  k_lift<<<65536, 256, 0, stream>>>(q, proj_w, proj_b, x);

  for (int d = 0; d < DEPTH; ++d){
    k_dftw<<<2048, 256, 0, stream>>>(x, ctab, stab, X1);
    k_dfth<<<dim3(64,4), 256, 0, stream>>>(X1, ctab, stab, Xfp);
    k_contract<<<64, 256, 0, stream>>>(Xfp, spec_wr + (size_t)d*1048576,
                                       spec_wi + (size_t)d*1048576, Y);
    k_idfth<<<2048, 256, 0, stream>>>(Y, ctab, stab, T);
    k_combine<<<dim3(2,512), 256, 0, stream>>>(x, T, wwT + d*4096, w_b + d*64,
                                               ctT, stT, x);
  }
  k_final<<<1024, 256, 0, stream>>>(x, final_w, final_b, out);
}

// Round 3
// 798.880 us; speedup vs baseline: 1.2921x; 1.2921x over previous
//
#include <hip/hip_runtime.h>
#include <cmath>

#define CC 64
#define HH 512
#define WWID 512
#define HWSZ (HH*WWID)
#define DEPTH 4

// ---------------- init: twiddle tables + transposed local weights ----------------
__global__ void k_twiddle(float* __restrict__ ctab, float* __restrict__ stab,
                          float* __restrict__ ctT, float* __restrict__ stT){
  int idx = blockIdx.x*256 + threadIdx.x;     // < 512*16
  int pos = idx >> 4, k = idx & 15;
  int r = (pos * k) & 511;
  double ang = (2.0 * 3.14159265358979323846 / 512.0) * (double)r;
  float c = (float)cos(ang), s = (float)sin(ang);
  ctab[idx] = c;  stab[idx] = s;
  ctT[k*512 + pos] = c;  stT[k*512 + pos] = s;
}

// transpose w_w[d][o][i] -> wwT[d][i][o]
__global__ void k_prep(const float* __restrict__ ww, float* __restrict__ wwT){
  int idx = blockIdx.x*256 + threadIdx.x;     // < 4*64*64
  int d = idx >> 12, r = idx & 4095, o = r >> 6, i = r & 63;
  wwT[(d<<12) + (i<<6) + o] = ww[idx];
}

// ---------------- lift: x[c,h,w] = proj_w[c]*q[h,w] + proj_b[c] ----------------
__global__ void k_lift(const float* __restrict__ q, const float* __restrict__ pw,
                       const float* __restrict__ pb, float* __restrict__ x){
  int idx = blockIdx.x*256 + threadIdx.x;     // < 64*HW
  int c = idx >> 18, p = idx & (HWSZ-1);
  x[idx] = fmaf(pw[c], q[p], pb[c]);
}

// ---------------- A: partial DFT along w: X1[i,h,n] = sum_w x * e^{-2pi i n w/512} ----------------
__global__ __launch_bounds__(256) void k_dftw(const float* __restrict__ x,
                       const float* __restrict__ ctab, const float* __restrict__ stab,
                       float2* __restrict__ X1){
  __shared__ float xs[16][513];
  int row0 = blockIdx.x * 16;
  for (int idx = threadIdx.x; idx < 16*512; idx += 256){
    int r = idx >> 9, w = idx & 511;
    xs[r][w] = x[(row0 + r)*512 + w];
  }
  __syncthreads();
  int r = threadIdx.x >> 4, n = threadIdx.x & 15;
  float ar = 0.f, ai = 0.f;
  #pragma unroll 8
  for (int w = 0; w < 512; ++w){
    float xv = xs[r][w];
    ar = fmaf(xv, ctab[w*16 + n], ar);
    ai = fmaf(xv, stab[w*16 + n], ai);
  }
  X1[(row0 + r)*16 + n] = make_float2(ar, -ai);
}

// ---------------- B1: partial DFT along h (chunked): Xfp[ch][i][m*16+n] ----------------
__global__ void k_dfth(const float2* __restrict__ X1, const float* __restrict__ ct,
                       const float* __restrict__ st, float2* __restrict__ Xfp){
  int i = blockIdx.x, ch = blockIdx.y;
  int m = threadIdx.x >> 4, n = threadIdx.x & 15;
  float ar = 0.f, ai = 0.f;
  int h0 = ch * 128;
  #pragma unroll 8
  for (int hh = 0; hh < 128; ++hh){
    int h = h0 + hh;
    float2 v = X1[(i*512 + h)*16 + n];
    float c = ct[h*16 + m], s = st[h*16 + m];
    ar += v.x*c + v.y*s;
    ai += v.y*c - v.x*s;
  }
  Xfp[(ch*64 + i)*256 + threadIdx.x] = make_float2(ar, ai);
}

// ---------------- B2: mode contraction, j-split into 4 partials ----------------
// Yp[(jc*64+o)*256+mn] = (1/HW) sum_{j in chunk jc} Xf[j,mn]*w[i(j),o,mn]
__global__ void k_contract(const float2* __restrict__ Xfp,
                           const float* __restrict__ wr, const float* __restrict__ wi,
                           float2* __restrict__ Yp){
  int o = blockIdx.x, jc = blockIdx.y, mn = threadIdx.x;
  float ar = 0.f, ai = 0.f;
  int j0 = jc * 64;
  #pragma unroll 4
  for (int jj = 0; jj < 64; ++jj){
    int j = j0 + jj;           // j = ch*64 + i, this chunk is ch=jc, i=jj
    float2 xf = Xfp[j*256 + mn];
    float wrv = wr[(jj*64 + o)*256 + mn];
    float wiv = wi[(jj*64 + o)*256 + mn];
    ar += xf.x*wrv - xf.y*wiv;
    ai += xf.x*wiv + xf.y*wrv;
  }
  const float sc = 1.f/262144.f;
  Yp[(jc*64 + o)*256 + mn] = make_float2(ar*sc, ai*sc);
}

// ---------------- B3: inverse DFT along h, summing 4 partials ----------------
__global__ void k_idfth(const float2* __restrict__ Yp, const float* __restrict__ ct,
                        const float* __restrict__ st, float2* __restrict__ T){
  int idx = blockIdx.x*256 + threadIdx.x;     // (h*64+o)*16+n
  int n = idx & 15, o = (idx >> 4) & 63, h = idx >> 10;
  float ar = 0.f, ai = 0.f;
  #pragma unroll
  for (int m = 0; m < 16; ++m){
    float yr = 0.f, yi = 0.f;
    #pragma unroll
    for (int jc = 0; jc < 4; ++jc){
      float2 y = Yp[((jc<<6) + o)*256 + (m<<4) + n];
      yr += y.x; yi += y.y;
    }
    float c = ct[h*16 + m], s = st[h*16 + m];
    ar += yr*c - yi*s;
    ai += yr*s + yi*c;
  }
  T[idx] = make_float2(ar, ai);
}

// ---------------- C: combine = gelu( iDFT_w(T) + local_conv(x) + b ), in-place ----------------
// block: 64 lanes (w) x 4 o-groups of 16 channels. acc[16] stays in VGPRs (no spill).
__global__ __launch_bounds__(256) void k_combine(
    const float* __restrict__ x, const float2* __restrict__ T,
    const float* __restrict__ wwT, const float* __restrict__ wb,
    const float* __restrict__ ctT, const float* __restrict__ stT,
    float* __restrict__ xo)
{
  __shared__ float xs[64][64];                // [i][lane], 16 KB, 2-way bank alias = free
  int h = blockIdx.y;
  int lane = threadIdx.x & 63;
  int g = threadIdx.x >> 6;
  int o0 = __builtin_amdgcn_readfirstlane(g << 4);   // wave-uniform -> keeps weight/T loads scalar
  int w = blockIdx.x*64 + lane;

  const float* xp = x + h*WWID + w;
  #pragma unroll
  for (int i = g; i < 64; i += 4) xs[i][lane] = xp[(size_t)i*HWSZ];
  __syncthreads();

  float acc[16];
  #pragma unroll
  for (int o = 0; o < 16; ++o) acc[o] = 0.f;

  // local 1x1 conv
  for (int i = 0; i < 64; ++i){
    float xv = xs[i][lane];
    const float* wrow = wwT + (i<<6) + o0;    // wave-uniform -> s_load
    #pragma unroll
    for (int o = 0; o < 16; ++o) acc[o] = fmaf(wrow[o], xv, acc[o]);
  }

  // spectral: Re( sum_n T[o,h,n] * e^{+2pi i n w/512} )
  float cv[16], sv[16];
  #pragma unroll
  for (int n = 0; n < 16; ++n){ cv[n] = ctT[n*512 + w]; sv[n] = stT[n*512 + w]; }
  const float2* Tp = T + h*1024 + (o0<<4);    // wave-uniform -> s_load
  #pragma unroll
  for (int o = 0; o < 16; ++o){
    float sacc = 0.f;
    #pragma unroll
    for (int n = 0; n < 16; ++n){
      float2 t = Tp[(o<<4) + n];
      sacc = fmaf(t.x, cv[n], sacc);
      sacc = fmaf(-t.y, sv[n], sacc);
    }
    acc[o] += sacc;
  }

  // bias + tanh-gelu + in-place store
  #pragma unroll
  for (int o = 0; o < 16; ++o){
    float u = acc[o] + wb[o0 + o];
    float z = 0.7978845608028654f * fmaf(0.044715f, u*u*u, u);
    float e = __expf(2.f*z);
    float gl = u - __fdividef(u, e + 1.f);
    xo[(size_t)(o0 + o)*HWSZ + h*WWID + w] = gl;
  }
}

// ---------------- final projection ----------------
__global__ void k_final(const float* __restrict__ x, const float* __restrict__ fw,
                        const float* __restrict__ fb, float* __restrict__ out){
  int p = blockIdx.x*256 + threadIdx.x;
  float acc = fb[0];
  #pragma unroll
  for (int i = 0; i < CC; ++i) acc = fmaf(fw[i], x[i*HWSZ + p], acc);
  out[p] = acc;
}

extern "C" void kernel_launch(void* const* d_in, const int* in_sizes, int n_in,
                              void* d_out, int out_size, void* d_ws, size_t ws_size,
                              hipStream_t stream) {
  const float* q       = (const float*)d_in[0];
  const float* proj_w  = (const float*)d_in[1];
  const float* proj_b  = (const float*)d_in[2];
  const float* spec_wr = (const float*)d_in[3];
  const float* spec_wi = (const float*)d_in[4];
  const float* w_w     = (const float*)d_in[5];
  const float* w_b     = (const float*)d_in[6];
  const float* final_w = (const float*)d_in[7];
  const float* final_b = (const float*)d_in[8];
  float* out = (float*)d_out;

  // Workspace layout — all offsets in BYTES, end = start + exact size:
  //   ctab   [       0,   32768)  512*16 f32
  //   stab   [   32768,   65536)
  //   ctT    [   65536,   98304)
  //   stT    [   98304,  131072)
  //   X1/T   [  131072, 4325376)  524288 float2 (4 MiB; T aliases X1, disjoint liveness)
  //   Xfp    [ 4325376, 4849664)  65536 float2 (512 KiB)
  //   Yp     [ 4849664, 5373952)  65536 float2 (512 KiB)  <-- R2 bug: x started at
  //   x      [ 5373952,72482816)  64 MiB                      5361664, 12 KB inside Yp
  //   wwT    [72482816,72548352)  64 KiB        total ~69.2 MiB
  char* ws = (char*)d_ws;
  float*  ctab = (float*) (ws + 0);
  float*  stab = (float*) (ws + 32768);
  float*  ctT  = (float*) (ws + 65536);
  float*  stT  = (float*) (ws + 98304);
  float2* X1   = (float2*)(ws + 131072);
  float2* T    = X1;
  float2* Xfp  = (float2*)(ws + 4325376);
  float2* Yp   = (float2*)(ws + 4849664);
  float*  x    = (float*) (ws + 5373952);
  float*  wwT  = (float*) (ws + 72482816);

  k_twiddle<<<32, 256, 0, stream>>>(ctab, stab, ctT, stT);
  k_prep<<<64, 256, 0, stream>>>(w_w, wwT);
  k_lift<<<65536, 256, 0, stream>>>(q, proj_w, proj_b, x);

  for (int d = 0; d < DEPTH; ++d){
    k_dftw<<<2048, 256, 0, stream>>>(x, ctab, stab, X1);
    k_dfth<<<dim3(64,4), 256, 0, stream>>>(X1, ctab, stab, Xfp);
    k_contract<<<dim3(64,4), 256, 0, stream>>>(Xfp, spec_wr + (size_t)d*1048576,
                                               spec_wi + (size_t)d*1048576, Yp);
    k_idfth<<<2048, 256, 0, stream>>>(Yp, ctab, stab, T);
    k_combine<<<dim3(8,512), 256, 0, stream>>>(x, T, wwT + d*4096, w_b + d*64,
                                               ctT, stT, x);
  }
  k_final<<<1024, 256, 0, stream>>>(x, final_w, final_b, out);
}

// Round 4
// 674.030 us; speedup vs baseline: 1.5315x; 1.1852x over previous
//
#include <hip/hip_runtime.h>
#include <cmath>

#define CC 64
#define HH 512
#define WWID 512
#define HWSZ (HH*WWID)
#define DEPTH 4

// ---------------- init: twiddle tables + transposed local weights ----------------
__global__ void k_twiddle(float* __restrict__ ctab, float* __restrict__ stab,
                          float* __restrict__ ctT, float* __restrict__ stT){
  int idx = blockIdx.x*256 + threadIdx.x;     // < 512*16
  int pos = idx >> 4, k = idx & 15;
  int r = (pos * k) & 511;
  double ang = (2.0 * 3.14159265358979323846 / 512.0) * (double)r;
  float c = (float)cos(ang), s = (float)sin(ang);
  ctab[idx] = c;  stab[idx] = s;
  ctT[k*512 + pos] = c;  stT[k*512 + pos] = s;
}

// transpose w_w[d][o][i] -> wwT[d][i][o]
__global__ void k_prep(const float* __restrict__ ww, float* __restrict__ wwT){
  int idx = blockIdx.x*256 + threadIdx.x;     // < 4*64*64
  int d = idx >> 12, r = idx & 4095, o = r >> 6, i = r & 63;
  wwT[(d<<12) + (i<<6) + o] = ww[idx];
}

// ---------------- lift: x[c,h,w] = proj_w[c]*q[h,w] + proj_b[c] ----------------
__global__ void k_lift(const float* __restrict__ q, const float* __restrict__ pw,
                       const float* __restrict__ pb, float* __restrict__ x){
  int idx = blockIdx.x*256 + threadIdx.x;     // < 64*HW
  int c = idx >> 18, p = idx & (HWSZ-1);
  x[idx] = fmaf(pw[c], q[p], pb[c]);
}

// ---------------- A: partial DFT along w, v2 ----------------
// Even/odd folding: X1[n] = x0 + (-1)^n x256 + sum_{w=1}^{255} (e_w cos - i o_w sin),
// twiddles generated by in-register rotation (4 phase pairs, step 4*delta).
__global__ __launch_bounds__(256) void k_dftw(const float* __restrict__ x,
                                              float2* __restrict__ X1){
  __shared__ float es[16][260];   // [r][w], w<256; rows 1040 B (16B-aligned, bank offset 4r)
  __shared__ float os[16][260];
  __shared__ float xm[16];        // x[256] per row
  int row0 = blockIdx.x * 16;

  // stage + fold: e_w = x[w]+x[512-w], o_w = x[w]-x[512-w]  (w=0: e=x0, o unused since sin0=0)
  for (int t = threadIdx.x; t < 4096; t += 256){
    int r = t >> 8, w = t & 255;
    const float* row = x + (size_t)(row0 + r)*512;
    float a = row[w];
    int mi = (w == 0) ? 256 : (512 - w);      // keep load in-bounds for w==0
    float b = row[mi];
    if (w == 0){ xm[r] = b; b = 0.f; }
    es[r][w] = a + b;
    os[r][w] = a - b;
  }
  __syncthreads();

  int r = threadIdx.x >> 4, n = threadIdx.x & 15;
  const float dl = 1.2271846303085129e-2f * (float)n;   // 2*pi*n/512
  float c[4], s[4];
  #pragma unroll
  for (int k = 0; k < 4; ++k) __sincosf(dl * (float)k, &s[k], &c[k]);
  float cd, sd; __sincosf(dl * 4.f, &sd, &cd);

  float ar[4] = {0.f,0.f,0.f,0.f}, ai[4] = {0.f,0.f,0.f,0.f};
  const float4* ep = (const float4*)(&es[r][0]);
  const float4* op = (const float4*)(&os[r][0]);
  #pragma unroll 2
  for (int b = 0; b < 64; ++b){
    float4 e = ep[b], o = op[b];
    ar[0] = fmaf(e.x, c[0], ar[0]); ai[0] = fmaf(o.x, s[0], ai[0]);
    ar[1] = fmaf(e.y, c[1], ar[1]); ai[1] = fmaf(o.y, s[1], ai[1]);
    ar[2] = fmaf(e.z, c[2], ar[2]); ai[2] = fmaf(o.z, s[2], ai[2]);
    ar[3] = fmaf(e.w, c[3], ar[3]); ai[3] = fmaf(o.w, s[3], ai[3]);
    #pragma unroll
    for (int k = 0; k < 4; ++k){
      float tc = fmaf(c[k], cd, -(s[k]*sd));
      float ts = fmaf(s[k], cd,  (c[k]*sd));
      c[k] = tc; s[k] = ts;
    }
  }
  float sgn = (n & 1) ? -1.f : 1.f;
  float arr = (ar[0]+ar[1]) + (ar[2]+ar[3]) + sgn*xm[r];
  float aii = (ai[0]+ai[1]) + (ai[2]+ai[3]);
  X1[(row0 + r)*16 + n] = make_float2(arr, -aii);
}

// ---------------- B1: partial DFT along h (8 chunks of 64): Xfp[ch][i][m*16+n] ----------------
__global__ void k_dfth(const float2* __restrict__ X1, const float* __restrict__ ct,
                       const float* __restrict__ st, float2* __restrict__ Xfp){
  int i = blockIdx.x, ch = blockIdx.y;
  int m = threadIdx.x >> 4, n = threadIdx.x & 15;
  float ar = 0.f, ai = 0.f;
  int h0 = ch * 64;
  #pragma unroll 8
  for (int hh = 0; hh < 64; ++hh){
    int h = h0 + hh;
    float2 v = X1[(i*512 + h)*16 + n];
    float c = ct[h*16 + m], s = st[h*16 + m];
    ar += v.x*c + v.y*s;
    ai += v.y*c - v.x*s;
  }
  Xfp[(ch*64 + i)*256 + threadIdx.x] = make_float2(ar, ai);
}

// ---------------- B2: mode contraction, j-split into 8 partials ----------------
__global__ void k_contract(const float2* __restrict__ Xfp,
                           const float* __restrict__ wr, const float* __restrict__ wi,
                           float2* __restrict__ Yp){
  int o = blockIdx.x, jc = blockIdx.y, mn = threadIdx.x;
  float ar = 0.f, ai = 0.f;
  int j0 = jc * 64;
  #pragma unroll 8
  for (int jj = 0; jj < 64; ++jj){
    int j = j0 + jj;           // j = ch*64 + i → this block: ch=jc, i=jj
    float2 xf = Xfp[j*256 + mn];
    float wrv = wr[(jj*64 + o)*256 + mn];
    float wiv = wi[(jj*64 + o)*256 + mn];
    ar += xf.x*wrv - xf.y*wiv;
    ai += xf.x*wiv + xf.y*wrv;
  }
  const float sc = 1.f/262144.f;
  Yp[(jc*64 + o)*256 + mn] = make_float2(ar*sc, ai*sc);
}

// ---------------- B3: inverse DFT along h, summing 8 partials ----------------
__global__ void k_idfth(const float2* __restrict__ Yp, const float* __restrict__ ct,
                        const float* __restrict__ st, float2* __restrict__ T){
  int idx = blockIdx.x*256 + threadIdx.x;     // (h*64+o)*16+n
  int n = idx & 15, o = (idx >> 4) & 63, h = idx >> 10;
  float ar = 0.f, ai = 0.f;
  #pragma unroll
  for (int m = 0; m < 16; ++m){
    float yr = 0.f, yi = 0.f;
    #pragma unroll
    for (int jc = 0; jc < 8; ++jc){
      float2 y = Yp[((jc<<6) + o)*256 + (m<<4) + n];
      yr += y.x; yi += y.y;
    }
    float c = ct[h*16 + m], s = st[h*16 + m];
    ar += yr*c - yi*s;
    ai += yr*s + yi*c;
  }
  T[idx] = make_float2(ar, ai);
}

// ---------------- C: combine = gelu( iDFT_w(T) + local_conv(x) + b ), in-place ----------------
__global__ __launch_bounds__(256) void k_combine(
    const float* __restrict__ x, const float2* __restrict__ T,
    const float* __restrict__ wwT, const float* __restrict__ wb,
    const float* __restrict__ ctT, const float* __restrict__ stT,
    float* __restrict__ xo)
{
  __shared__ float xs[64][64];                // [i][lane], 16 KB, 2-way bank alias = free
  int h = blockIdx.y;
  int lane = threadIdx.x & 63;
  int g = threadIdx.x >> 6;
  int o0 = __builtin_amdgcn_readfirstlane(g << 4);   // wave-uniform -> scalar weight/T loads
  int w = blockIdx.x*64 + lane;

  const float* xp = x + h*WWID + w;
  #pragma unroll
  for (int i = g; i < 64; i += 4) xs[i][lane] = xp[(size_t)i*HWSZ];
  __syncthreads();

  float acc[16];
  #pragma unroll
  for (int o = 0; o < 16; ++o) acc[o] = 0.f;

  for (int i = 0; i < 64; ++i){
    float xv = xs[i][lane];
    const float* wrow = wwT + (i<<6) + o0;
    #pragma unroll
    for (int o = 0; o < 16; ++o) acc[o] = fmaf(wrow[o], xv, acc[o]);
  }

  float cv[16], sv[16];
  #pragma unroll
  for (int n = 0; n < 16; ++n){ cv[n] = ctT[n*512 + w]; sv[n] = stT[n*512 + w]; }
  const float2* Tp = T + h*1024 + (o0<<4);
  #pragma unroll
  for (int o = 0; o < 16; ++o){
    float sacc = 0.f;
    #pragma unroll
    for (int n = 0; n < 16; ++n){
      float2 t = Tp[(o<<4) + n];
      sacc = fmaf(t.x, cv[n], sacc);
      sacc = fmaf(-t.y, sv[n], sacc);
    }
    acc[o] += sacc;
  }

  #pragma unroll
  for (int o = 0; o < 16; ++o){
    float u = acc[o] + wb[o0 + o];
    float z = 0.7978845608028654f * fmaf(0.044715f, u*u*u, u);
    float e = __expf(2.f*z);
    float gl = u - __fdividef(u, e + 1.f);
    xo[(size_t)(o0 + o)*HWSZ + h*WWID + w] = gl;
  }
}

// ---------------- final projection ----------------
__global__ void k_final(const float* __restrict__ x, const float* __restrict__ fw,
                        const float* __restrict__ fb, float* __restrict__ out){
  int p = blockIdx.x*256 + threadIdx.x;
  float acc = fb[0];
  #pragma unroll
  for (int i = 0; i < CC; ++i) acc = fmaf(fw[i], x[i*HWSZ + p], acc);
  out[p] = acc;
}

extern "C" void kernel_launch(void* const* d_in, const int* in_sizes, int n_in,
                              void* d_out, int out_size, void* d_ws, size_t ws_size,
                              hipStream_t stream) {
  const float* q       = (const float*)d_in[0];
  const float* proj_w  = (const float*)d_in[1];
  const float* proj_b  = (const float*)d_in[2];
  const float* spec_wr = (const float*)d_in[3];
  const float* spec_wi = (const float*)d_in[4];
  const float* w_w     = (const float*)d_in[5];
  const float* w_b     = (const float*)d_in[6];
  const float* final_w = (const float*)d_in[7];
  const float* final_b = (const float*)d_in[8];
  float* out = (float*)d_out;

  // Workspace layout (bytes, end-exclusive):
  //   ctab [       0,   32768)
  //   stab [   32768,   65536)
  //   ctT  [   65536,   98304)
  //   stT  [   98304,  131072)
  //   X1/T [  131072,  4325376)  4 MiB (T aliases X1; disjoint liveness)
  //   Xfp  [ 4325376,  5373952)  1 MiB (8 h-chunks)
  //   Yp   [ 5373952,  6422528)  1 MiB (8 j-chunks)
  //   x    [ 6422528, 73531392)  64 MiB
  //   wwT  [73531392, 73596928)  64 KiB   total ~70.2 MiB (<76.3 MiB proven in R1)
  char* ws = (char*)d_ws;
  float*  ctab = (float*) (ws + 0);
  float*  stab = (float*) (ws + 32768);
  float*  ctT  = (float*) (ws + 65536);
  float*  stT  = (float*) (ws + 98304);
  float2* X1   = (float2*)(ws + 131072);
  float2* T    = X1;
  float2* Xfp  = (float2*)(ws + 4325376);
  float2* Yp   = (float2*)(ws + 5373952);
  float*  x    = (float*) (ws + 6422528);
  float*  wwT  = (float*) (ws + 73531392);

  k_twiddle<<<32, 256, 0, stream>>>(ctab, stab, ctT, stT);
  k_prep<<<64, 256, 0, stream>>>(w_w, wwT);
  k_lift<<<65536, 256, 0, stream>>>(q, proj_w, proj_b, x);

  for (int d = 0; d < DEPTH; ++d){
    k_dftw<<<2048, 256, 0, stream>>>(x, X1);
    k_dfth<<<dim3(64,8), 256, 0, stream>>>(X1, ctab, stab, Xfp);
    k_contract<<<dim3(64,8), 256, 0, stream>>>(Xfp, spec_wr + (size_t)d*1048576,
                                               spec_wi + (size_t)d*1048576, Yp);
    k_idfth<<<2048, 256, 0, stream>>>(Yp, ctab, stab, T);
    k_combine<<<dim3(8,512), 256, 0, stream>>>(x, T, wwT + d*4096, w_b + d*64,
                                               ctT, stT, x);
  }
  k_final<<<1024, 256, 0, stream>>>(x, final_w, final_b, out);
}

// Round 5
// 588.992 us; speedup vs baseline: 1.7526x; 1.1444x over previous
//
#include <hip/hip_runtime.h>
#include <cmath>

#define CC 64
#define HH 512
#define WWID 512
#define HWSZ (HH*WWID)
#define DEPTH 4

// ---------------- init: twiddle tables + transposed local weights (fused) ----------------
__global__ void k_init(const float* __restrict__ ww,
                       float* __restrict__ ctab, float* __restrict__ stab,
                       float* __restrict__ ctT, float* __restrict__ stT,
                       float* __restrict__ wwT){
  int idx = blockIdx.x*256 + threadIdx.x;
  if (idx < 8192){
    int pos = idx >> 4, k = idx & 15;
    int r = (pos * k) & 511;
    double ang = (2.0 * 3.14159265358979323846 / 512.0) * (double)r;
    float c = (float)cos(ang), s = (float)sin(ang);
    ctab[idx] = c;  stab[idx] = s;
    ctT[k*512 + pos] = c;  stT[k*512 + pos] = s;
  } else {
    int t = idx - 8192;                       // < 4*64*64
    int d = t >> 12, r2 = t & 4095, o = r2 >> 6, i = r2 & 63;
    wwT[(d<<12) + (i<<6) + o] = ww[t];
  }
}

// ---------------- lift: x[c,h,w] = proj_w[c]*q[h,w] + proj_b[c] ----------------
__global__ void k_lift(const float* __restrict__ q, const float* __restrict__ pw,
                       const float* __restrict__ pb, float* __restrict__ x){
  int idx = blockIdx.x*256 + threadIdx.x;     // < 64*HW
  int c = idx >> 18, p = idx & (HWSZ-1);
  x[idx] = fmaf(pw[c], q[p], pb[c]);
}

// ---------------- A: partial DFT along w (even/odd fold + in-register twiddle rotation) ----------------
__global__ __launch_bounds__(256) void k_dftw(const float* __restrict__ x,
                                              float2* __restrict__ X1){
  __shared__ float es[16][260];
  __shared__ float os[16][260];
  __shared__ float xm[16];
  int row0 = blockIdx.x * 16;

  for (int t = threadIdx.x; t < 4096; t += 256){
    int r = t >> 8, w = t & 255;
    const float* row = x + (size_t)(row0 + r)*512;
    float a = row[w];
    int mi = (w == 0) ? 256 : (512 - w);
    float b = row[mi];
    if (w == 0){ xm[r] = b; b = 0.f; }
    es[r][w] = a + b;
    os[r][w] = a - b;
  }
  __syncthreads();

  int r = threadIdx.x >> 4, n = threadIdx.x & 15;
  const float dl = 1.2271846303085129e-2f * (float)n;   // 2*pi*n/512
  float c[4], s[4];
  #pragma unroll
  for (int k = 0; k < 4; ++k) __sincosf(dl * (float)k, &s[k], &c[k]);
  float cd, sd; __sincosf(dl * 4.f, &sd, &cd);

  float ar[4] = {0.f,0.f,0.f,0.f}, ai[4] = {0.f,0.f,0.f,0.f};
  const float4* ep = (const float4*)(&es[r][0]);
  const float4* op = (const float4*)(&os[r][0]);
  #pragma unroll 2
  for (int b = 0; b < 64; ++b){
    float4 e = ep[b], o = op[b];
    ar[0] = fmaf(e.x, c[0], ar[0]); ai[0] = fmaf(o.x, s[0], ai[0]);
    ar[1] = fmaf(e.y, c[1], ar[1]); ai[1] = fmaf(o.y, s[1], ai[1]);
    ar[2] = fmaf(e.z, c[2], ar[2]); ai[2] = fmaf(o.z, s[2], ai[2]);
    ar[3] = fmaf(e.w, c[3], ar[3]); ai[3] = fmaf(o.w, s[3], ai[3]);
    #pragma unroll
    for (int k = 0; k < 4; ++k){
      float tc = fmaf(c[k], cd, -(s[k]*sd));
      float ts = fmaf(s[k], cd,  (c[k]*sd));
      c[k] = tc; s[k] = ts;
    }
  }
  float sgn = (n & 1) ? -1.f : 1.f;
  float arr = (ar[0]+ar[1]) + (ar[2]+ar[3]) + sgn*xm[r];
  float aii = (ai[0]+ai[1]) + (ai[2]+ai[3]);
  X1[(row0 + r)*16 + n] = make_float2(arr, -aii);
}

// ---------------- B1: partial DFT along h (16 chunks of 32): Xfp[ch][i][mn] ----------------
__global__ void k_dfth(const float2* __restrict__ X1, const float* __restrict__ ct,
                       const float* __restrict__ st, float2* __restrict__ Xfp){
  int i = blockIdx.x, ch = blockIdx.y;
  int m = threadIdx.x >> 4, n = threadIdx.x & 15;
  float ar = 0.f, ai = 0.f;
  int h0 = ch * 32;
  #pragma unroll 8
  for (int hh = 0; hh < 32; ++hh){
    int h = h0 + hh;
    float2 v = X1[(i*512 + h)*16 + n];
    float c = ct[h*16 + m], s = st[h*16 + m];
    ar += v.x*c + v.y*s;
    ai += v.y*c - v.x*s;
  }
  Xfp[(ch*64 + i)*256 + threadIdx.x] = make_float2(ar, ai);
}

// ---------------- B1b: reduce h-chunk partials: Xf[i][mn] = sum_ch Xfp ----------------
__global__ void k_redXf(const float2* __restrict__ Xfp, float2* __restrict__ Xf){
  int i = blockIdx.x, mn = threadIdx.x;
  float ar = 0.f, ai = 0.f;
  #pragma unroll
  for (int ch = 0; ch < 16; ++ch){
    float2 v = Xfp[(ch*64 + i)*256 + mn];
    ar += v.x; ai += v.y;
  }
  Xf[i*256 + mn] = make_float2(ar, ai);
}

// ---------------- B2: mode contraction, i-chunked (weights read exactly once) ----------------
__global__ void k_contract(const float2* __restrict__ Xf,
                           const float* __restrict__ wr, const float* __restrict__ wi,
                           float2* __restrict__ Yp){
  int o = blockIdx.x, ic = blockIdx.y, mn = threadIdx.x;
  float ar = 0.f, ai = 0.f;
  int i0 = ic * 16;
  #pragma unroll
  for (int ii = 0; ii < 16; ++ii){
    int i = i0 + ii;
    float2 xf = Xf[i*256 + mn];
    float wrv = wr[(i*64 + o)*256 + mn];
    float wiv = wi[(i*64 + o)*256 + mn];
    ar += xf.x*wrv - xf.y*wiv;
    ai += xf.x*wiv + xf.y*wrv;
  }
  const float sc = 1.f/262144.f;
  Yp[(ic*64 + o)*256 + mn] = make_float2(ar*sc, ai*sc);
}

// ---------------- B3: inverse DFT along h, summing 4 partials ----------------
__global__ void k_idfth(const float2* __restrict__ Yp, const float* __restrict__ ct,
                        const float* __restrict__ st, float2* __restrict__ T){
  int idx = blockIdx.x*256 + threadIdx.x;     // (h*64+o)*16+n
  int n = idx & 15, o = (idx >> 4) & 63, h = idx >> 10;
  float ar = 0.f, ai = 0.f;
  #pragma unroll
  for (int m = 0; m < 16; ++m){
    float yr = 0.f, yi = 0.f;
    #pragma unroll
    for (int jc = 0; jc < 4; ++jc){
      float2 y = Yp[((jc<<6) + o)*256 + (m<<4) + n];
      yr += y.x; yi += y.y;
    }
    float c = ct[h*16 + m], s = st[h*16 + m];
    ar += yr*c - yi*s;
    ai += yr*s + yi*c;
  }
  T[idx] = make_float2(ar, ai);
}

// ---------------- C: combine = gelu( iDFT_w(T) + local_conv(x) + b ), in-place ----------------
// v3: spectral FIRST with n-outer loop (cv/sv = 2 live regs), then conv, then gelu.
__global__ __launch_bounds__(256) void k_combine(
    const float* __restrict__ x, const float2* __restrict__ T,
    const float* __restrict__ wwT, const float* __restrict__ wb,
    const float* __restrict__ ctT, const float* __restrict__ stT,
    float* __restrict__ xo)
{
  __shared__ float xs[64][64];
  int h = blockIdx.y;
  int lane = threadIdx.x & 63;
  int g = threadIdx.x >> 6;
  int o0 = __builtin_amdgcn_readfirstlane(g << 4);   // wave-uniform -> scalar T/weight loads
  int w = blockIdx.x*64 + lane;

  const float* xp = x + h*WWID + w;
  #pragma unroll
  for (int i = g; i < 64; i += 4) xs[i][lane] = xp[(size_t)i*HWSZ];

  float acc[16];
  #pragma unroll
  for (int o = 0; o < 16; ++o) acc[o] = 0.f;

  // spectral: acc[o] += Re( T[o,h,n] * e^{+i 2pi n w/512} ), n outer
  const float2* Tp = T + h*1024 + (o0<<4);
  #pragma unroll
  for (int n = 0; n < 16; ++n){
    float cvn = ctT[(n<<9) + w];
    float svn = stT[(n<<9) + w];
    #pragma unroll
    for (int o = 0; o < 16; ++o){
      float2 t = Tp[(o<<4) + n];
      acc[o] = fmaf(t.x, cvn, acc[o]);
      acc[o] = fmaf(-t.y, svn, acc[o]);
    }
  }
  __syncthreads();

  // local 1x1 conv
  for (int i = 0; i < 64; ++i){
    float xv = xs[i][lane];
    const float* wrow = wwT + (i<<6) + o0;
    #pragma unroll
    for (int o = 0; o < 16; ++o) acc[o] = fmaf(wrow[o], xv, acc[o]);
  }

  // bias + tanh-gelu + in-place store
  #pragma unroll
  for (int o = 0; o < 16; ++o){
    float u = acc[o] + wb[o0 + o];
    float z = 0.7978845608028654f * fmaf(0.044715f, u*u*u, u);
    float e = __expf(2.f*z);
    float gl = u - __fdividef(u, e + 1.f);
    xo[(size_t)(o0 + o)*HWSZ + h*WWID + w] = gl;
  }
}

// ---------------- final projection ----------------
__global__ void k_final(const float* __restrict__ x, const float* __restrict__ fw,
                        const float* __restrict__ fb, float* __restrict__ out){
  int p = blockIdx.x*256 + threadIdx.x;
  float acc = fb[0];
  #pragma unroll
  for (int i = 0; i < CC; ++i) acc = fmaf(fw[i], x[i*HWSZ + p], acc);
  out[p] = acc;
}

extern "C" void kernel_launch(void* const* d_in, const int* in_sizes, int n_in,
                              void* d_out, int out_size, void* d_ws, size_t ws_size,
                              hipStream_t stream) {
  const float* q       = (const float*)d_in[0];
  const float* proj_w  = (const float*)d_in[1];
  const float* proj_b  = (const float*)d_in[2];
  const float* spec_wr = (const float*)d_in[3];
  const float* spec_wi = (const float*)d_in[4];
  const float* w_w     = (const float*)d_in[5];
  const float* w_b     = (const float*)d_in[6];
  const float* final_w = (const float*)d_in[7];
  const float* final_b = (const float*)d_in[8];
  float* out = (float*)d_out;

  // Workspace (bytes, end-exclusive):
  //   ctab [       0,   32768)
  //   stab [   32768,   65536)
  //   ctT  [   65536,   98304)
  //   stT  [   98304,  131072)
  //   X1/T [  131072,  4325376)  4 MiB (alias; X1 dead before idfth writes T)
  //   Xfp  [ 4325376,  6422528)  2 MiB (16 h-chunks)
  //   Xf   [ 6422528,  6553600)  128 KiB
  //   Yp   [ 6553600,  7077888)  512 KiB (4 i-chunks)
  //   x    [ 7077888, 74186752)  64 MiB
  //   wwT  [74186752, 74252288)  64 KiB   total ~70.8 MiB (< 76.3 MiB proven)
  char* ws = (char*)d_ws;
  float*  ctab = (float*) (ws + 0);
  float*  stab = (float*) (ws + 32768);
  float*  ctT  = (float*) (ws + 65536);
  float*  stT  = (float*) (ws + 98304);
  float2* X1   = (float2*)(ws + 131072);
  float2* T    = X1;
  float2* Xfp  = (float2*)(ws + 4325376);
  float2* Xf   = (float2*)(ws + 6422528);
  float2* Yp   = (float2*)(ws + 6553600);
  float*  x    = (float*) (ws + 7077888);
  float*  wwT  = (float*) (ws + 74186752);

  k_init<<<96, 256, 0, stream>>>(w_w, ctab, stab, ctT, stT, wwT);
  k_lift<<<65536, 256, 0, stream>>>(q, proj_w, proj_b, x);

  for (int d = 0; d < DEPTH; ++d){
    k_dftw<<<2048, 256, 0, stream>>>(x, X1);
    k_dfth<<<dim3(64,16), 256, 0, stream>>>(X1, ctab, stab, Xfp);
    k_redXf<<<64, 256, 0, stream>>>(Xfp, Xf);
    k_contract<<<dim3(64,4), 256, 0, stream>>>(Xf, spec_wr + (size_t)d*1048576,
                                               spec_wi + (size_t)d*1048576, Yp);
    k_idfth<<<2048, 256, 0, stream>>>(Yp, ctab, stab, T);
    k_combine<<<dim3(8,512), 256, 0, stream>>>(x, T, wwT + d*4096, w_b + d*64,
                                               ctT, stT, x);
  }
  k_final<<<1024, 256, 0, stream>>>(x, final_w, final_b, out);
}

// Round 6
// 470.410 us; speedup vs baseline: 2.1944x; 1.2521x over previous
//
#include <hip/hip_runtime.h>
#include <cmath>

#define CC 64
#define HH 512
#define WWID 512
#define HWSZ (HH*WWID)
#define DEPTH 4

typedef __attribute__((ext_vector_type(8))) short short8;
typedef __attribute__((ext_vector_type(4))) float floatx4;

__device__ inline unsigned short f2bf(float f){
  unsigned int u = __float_as_uint(f);
  u += 0x7FFF + ((u >> 16) & 1);          // round-to-nearest-even
  return (unsigned short)(u >> 16);
}
__device__ inline float bf2f(unsigned short h){
  return __uint_as_float(((unsigned int)h) << 16);
}

// ---------------- init: fp32 twiddles (DFT kernels) + bf16 split trig/W (combine GEMM) ----------------
// trigB[w][2n]=cos(2pi n w/512), [2n+1]=sin(...) as bf16 hi + residual lo.
// W[d][o][i] split to bf16 hi/lo (natural layout = A-operand rows).
__global__ void k_init(const float* __restrict__ ww,
                       float* __restrict__ ctab, float* __restrict__ stab,
                       unsigned short* __restrict__ trigBh, unsigned short* __restrict__ trigBl,
                       unsigned short* __restrict__ Whi, unsigned short* __restrict__ Wlo){
  int idx = blockIdx.x*256 + threadIdx.x;
  if (idx < 8192){
    int pos = idx >> 4, k = idx & 15;
    int r = (pos * k) & 511;
    double ang = (2.0 * 3.14159265358979323846 / 512.0) * (double)r;
    float c = (float)cos(ang), s = (float)sin(ang);
    ctab[idx] = c;  stab[idx] = s;
    unsigned short ch = f2bf(c), sh = f2bf(s);
    trigBh[pos*32 + 2*k]     = ch;  trigBl[pos*32 + 2*k]     = f2bf(c - bf2f(ch));
    trigBh[pos*32 + 2*k + 1] = sh;  trigBl[pos*32 + 2*k + 1] = f2bf(s - bf2f(sh));
  } else {
    int t = idx - 8192;                   // < 4*64*64, flat [d][o][i]
    float v = ww[t];
    unsigned short h = f2bf(v);
    Whi[t] = h;  Wlo[t] = f2bf(v - bf2f(h));
  }
}

// ---------------- lift: x[c,h,w] = proj_w[c]*q[h,w] + proj_b[c] ----------------
__global__ void k_lift(const float* __restrict__ q, const float* __restrict__ pw,
                       const float* __restrict__ pb, float* __restrict__ x){
  int idx = blockIdx.x*256 + threadIdx.x;     // < 64*HW
  int c = idx >> 18, p = idx & (HWSZ-1);
  x[idx] = fmaf(pw[c], q[p], pb[c]);
}

// ---------------- A: partial DFT along w (even/odd fold + in-register twiddle rotation) ----------------
__global__ __launch_bounds__(256) void k_dftw(const float* __restrict__ x,
                                              float2* __restrict__ X1){
  __shared__ float es[16][260];
  __shared__ float os[16][260];
  __shared__ float xm[16];
  int row0 = blockIdx.x * 16;

  for (int t = threadIdx.x; t < 4096; t += 256){
    int r = t >> 8, w = t & 255;
    const float* row = x + (size_t)(row0 + r)*512;
    float a = row[w];
    int mi = (w == 0) ? 256 : (512 - w);
    float b = row[mi];
    if (w == 0){ xm[r] = b; b = 0.f; }
    es[r][w] = a + b;
    os[r][w] = a - b;
  }
  __syncthreads();

  int r = threadIdx.x >> 4, n = threadIdx.x & 15;
  const float dl = 1.2271846303085129e-2f * (float)n;   // 2*pi*n/512
  float c[4], s[4];
  #pragma unroll
  for (int k = 0; k < 4; ++k) __sincosf(dl * (float)k, &s[k], &c[k]);
  float cd, sd; __sincosf(dl * 4.f, &sd, &cd);

  float ar[4] = {0.f,0.f,0.f,0.f}, ai[4] = {0.f,0.f,0.f,0.f};
  const float4* ep = (const float4*)(&es[r][0]);
  const float4* op = (const float4*)(&os[r][0]);
  #pragma unroll 2
  for (int b = 0; b < 64; ++b){
    float4 e = ep[b], o = op[b];
    ar[0] = fmaf(e.x, c[0], ar[0]); ai[0] = fmaf(o.x, s[0], ai[0]);
    ar[1] = fmaf(e.y, c[1], ar[1]); ai[1] = fmaf(o.y, s[1], ai[1]);
    ar[2] = fmaf(e.z, c[2], ar[2]); ai[2] = fmaf(o.z, s[2], ai[2]);
    ar[3] = fmaf(e.w, c[3], ar[3]); ai[3] = fmaf(o.w, s[3], ai[3]);
    #pragma unroll
    for (int k = 0; k < 4; ++k){
      float tc = fmaf(c[k], cd, -(s[k]*sd));
      float ts = fmaf(s[k], cd,  (c[k]*sd));
      c[k] = tc; s[k] = ts;
    }
  }
  float sgn = (n & 1) ? -1.f : 1.f;
  float arr = (ar[0]+ar[1]) + (ar[2]+ar[3]) + sgn*xm[r];
  float aii = (ai[0]+ai[1]) + (ai[2]+ai[3]);
  X1[(row0 + r)*16 + n] = make_float2(arr, -aii);
}

// ---------------- B1: partial DFT along h (16 chunks of 32): Xfp[ch][i][mn] ----------------
__global__ void k_dfth(const float2* __restrict__ X1, const float* __restrict__ ct,
                       const float* __restrict__ st, float2* __restrict__ Xfp){
  int i = blockIdx.x, ch = blockIdx.y;
  int m = threadIdx.x >> 4, n = threadIdx.x & 15;
  float ar = 0.f, ai = 0.f;
  int h0 = ch * 32;
  #pragma unroll 8
  for (int hh = 0; hh < 32; ++hh){
    int h = h0 + hh;
    float2 v = X1[(i*512 + h)*16 + n];
    float c = ct[h*16 + m], s = st[h*16 + m];
    ar += v.x*c + v.y*s;
    ai += v.y*c - v.x*s;
  }
  Xfp[(ch*64 + i)*256 + threadIdx.x] = make_float2(ar, ai);
}

// ---------------- B1b: reduce h-chunk partials ----------------
__global__ void k_redXf(const float2* __restrict__ Xfp, float2* __restrict__ Xf){
  int i = blockIdx.x, mn = threadIdx.x;
  float ar = 0.f, ai = 0.f;
  #pragma unroll
  for (int ch = 0; ch < 16; ++ch){
    float2 v = Xfp[(ch*64 + i)*256 + mn];
    ar += v.x; ai += v.y;
  }
  Xf[i*256 + mn] = make_float2(ar, ai);
}

// ---------------- B2: mode contraction, i-chunked ----------------
__global__ void k_contract(const float2* __restrict__ Xf,
                           const float* __restrict__ wr, const float* __restrict__ wi,
                           float2* __restrict__ Yp){
  int o = blockIdx.x, ic = blockIdx.y, mn = threadIdx.x;
  float ar = 0.f, ai = 0.f;
  int i0 = ic * 16;
  #pragma unroll
  for (int ii = 0; ii < 16; ++ii){
    int i = i0 + ii;
    float2 xf = Xf[i*256 + mn];
    float wrv = wr[(i*64 + o)*256 + mn];
    float wiv = wi[(i*64 + o)*256 + mn];
    ar += xf.x*wrv - xf.y*wiv;
    ai += xf.x*wiv + xf.y*wrv;
  }
  const float sc = 1.f/262144.f;
  Yp[(ic*64 + o)*256 + mn] = make_float2(ar*sc, ai*sc);
}

// ---------------- B3: inverse DFT along h -> T, pre-split to bf16 hi/lo for combine's A-tile ----------------
// Thi[h][o][2n] = Tr, Thi[h][o][2n+1] = -Ti  (sign folded so combine's B trig rows are [cos | sin])
__global__ void k_idfth(const float2* __restrict__ Yp, const float* __restrict__ ct,
                        const float* __restrict__ st,
                        unsigned short* __restrict__ Thi, unsigned short* __restrict__ Tlo){
  int idx = blockIdx.x*256 + threadIdx.x;     // (h*64+o)*16+n
  int n = idx & 15, o = (idx >> 4) & 63, h = idx >> 10;
  float ar = 0.f, ai = 0.f;
  #pragma unroll
  for (int m = 0; m < 16; ++m){
    float yr = 0.f, yi = 0.f;
    #pragma unroll
    for (int jc = 0; jc < 4; ++jc){
      float2 y = Yp[((jc<<6) + o)*256 + (m<<4) + n];
      yr += y.x; yi += y.y;
    }
    float c = ct[h*16 + m], s = st[h*16 + m];
    ar += yr*c - yi*s;
    ai += yr*s + yi*c;
  }
  float tr = ar, ts = -ai;
  unsigned short rh = f2bf(tr), sh = f2bf(ts);
  size_t base = ((size_t)(h*64 + o))*32 + 2*n;
  Thi[base] = rh;  Thi[base+1] = sh;
  Tlo[base] = f2bf(tr - bf2f(rh));  Tlo[base+1] = f2bf(ts - bf2f(sh));
}

// ---------------- C: combine as one MFMA GEMM: D[o][w] = sum_K A[o][k] B[w][k], K=96 ----------------
// k<64: A=W rows, B=x pixels (split-bf16). k=64..95: A=[Tr|-Ti] per h, B=[cos|sin] per w.
// 3-pass split: AhBh + AhBl + AlBh (error ~2^-17). Epilogue: +bias, tanh-gelu, in-place store.
#define PITCH 104   // bf16 elts/row: 208 B = 52 dwords -> b128 16B-aligned, 2-way bank alias (free)
__global__ __launch_bounds__(256) void k_combine(
    const float* __restrict__ x,
    const unsigned short* __restrict__ Whid, const unsigned short* __restrict__ Wlod,
    const unsigned short* __restrict__ Thi,  const unsigned short* __restrict__ Tlo,
    const unsigned short* __restrict__ trigBh, const unsigned short* __restrict__ trigBl,
    const float* __restrict__ wb, float* __restrict__ xo)
{
  __shared__ unsigned short Ah[64*PITCH], Al[64*PITCH];   // rows o, k 0..95
  __shared__ unsigned short Bh[64*PITCH], Bl[64*PITCH];   // rows w(pixel), k 0..95
  int h  = blockIdx.y;
  int w0 = blockIdx.x * 64;
  int t  = threadIdx.x;

  // ---- stage B x-part: thread (wl, ig): 16 i's, coalesced global reads, packed b32 LDS writes
  {
    int wl = t & 63, ig = t >> 6;
    const float* xb = x + (size_t)h*512 + w0 + wl;
    #pragma unroll
    for (int ii = 0; ii < 16; ii += 2){
      int i0 = ig*16 + ii;
      float v0 = xb[(size_t)i0*HWSZ];
      float v1 = xb[(size_t)(i0+1)*HWSZ];
      unsigned short h0 = f2bf(v0), h1 = f2bf(v1);
      unsigned short g0 = f2bf(v0 - bf2f(h0)), g1 = f2bf(v1 - bf2f(h1));
      *(unsigned int*)&Bh[wl*PITCH + i0] = (unsigned int)h0 | ((unsigned int)h1 << 16);
      *(unsigned int*)&Bl[wl*PITCH + i0] = (unsigned int)g0 | ((unsigned int)g1 << 16);
    }
  }
  // ---- stage B trig-part: rows w, k=64..95 (16 uints/row)
  {
    int row = t >> 2, qq = t & 3;
    const unsigned int* sh = (const unsigned int*)trigBh + (size_t)(w0+row)*16 + qq*4;
    const unsigned int* sl = (const unsigned int*)trigBl + (size_t)(w0+row)*16 + qq*4;
    unsigned int* dh = (unsigned int*)&Bh[row*PITCH + 64] + qq*4;
    unsigned int* dl = (unsigned int*)&Bl[row*PITCH + 64] + qq*4;
    #pragma unroll
    for (int u = 0; u < 4; ++u){ dh[u] = sh[u]; dl[u] = sl[u]; }
  }
  // ---- stage A W-part: rows o, k=0..63 (32 uints/row, 8/thread)
  {
    int o = t >> 2, q8 = t & 3;
    const unsigned int* sh = (const unsigned int*)Whid + o*32 + q8*8;
    const unsigned int* sl = (const unsigned int*)Wlod + o*32 + q8*8;
    unsigned int* dh = (unsigned int*)&Ah[o*PITCH] + q8*8;
    unsigned int* dl = (unsigned int*)&Al[o*PITCH] + q8*8;
    #pragma unroll
    for (int u = 0; u < 8; ++u){ dh[u] = sh[u]; dl[u] = sl[u]; }
  }
  // ---- stage A T-part: rows o, k=64..95 (16 uints/row, 4/thread)
  {
    int o = t >> 2, q4 = t & 3;
    const unsigned int* sh = (const unsigned int*)Thi + (size_t)h*1024 + o*16 + q4*4;
    const unsigned int* sl = (const unsigned int*)Tlo + (size_t)h*1024 + o*16 + q4*4;
    unsigned int* dh = (unsigned int*)&Ah[o*PITCH + 64] + q4*4;
    unsigned int* dl = (unsigned int*)&Al[o*PITCH + 64] + q4*4;
    #pragma unroll
    for (int u = 0; u < 4; ++u){ dh[u] = sh[u]; dl[u] = sl[u]; }
  }
  __syncthreads();

  int g  = t >> 6;          // wave id -> m-tile (o-rows g*16..g*16+15)
  int lm = t & 15;          // lane&15
  int lq = (t >> 4) & 3;    // quad

  floatx4 acc[4] = {{0.f,0.f,0.f,0.f},{0.f,0.f,0.f,0.f},{0.f,0.f,0.f,0.f},{0.f,0.f,0.f,0.f}};

  #pragma unroll
  for (int p = 0; p < 3; ++p){
    const unsigned short* At = (p < 2) ? Ah : Al;
    const unsigned short* Bt = (p == 1) ? Bl : Bh;
    #pragma unroll
    for (int ks = 0; ks < 3; ++ks){
      short8 af = *(const short8*)&At[(g*16 + lm)*PITCH + ks*32 + lq*8];
      #pragma unroll
      for (int nt = 0; nt < 4; ++nt){
        short8 bf = *(const short8*)&Bt[(nt*16 + lm)*PITCH + ks*32 + lq*8];
        acc[nt] = __builtin_amdgcn_mfma_f32_16x16x32_bf16(af, bf, acc[nt], 0, 0, 0);
      }
    }
  }

  // ---- epilogue: bias + tanh-gelu + store (D: row=o=g*16+lq*4+reg, col=w=nt*16+lm)
  #pragma unroll
  for (int nt = 0; nt < 4; ++nt){
    int w = w0 + nt*16 + lm;
    #pragma unroll
    for (int rg = 0; rg < 4; ++rg){
      int o = g*16 + lq*4 + rg;
      float u = acc[nt][rg] + wb[o];
      float z = 0.7978845608028654f * fmaf(0.044715f, u*u*u, u);
      float e = __expf(2.f*z);
      float gl = u - __fdividef(u, e + 1.f);
      xo[(size_t)o*HWSZ + (size_t)h*512 + w] = gl;
    }
  }
}

// ---------------- final projection ----------------
__global__ void k_final(const float* __restrict__ x, const float* __restrict__ fw,
                        const float* __restrict__ fb, float* __restrict__ out){
  int p = blockIdx.x*256 + threadIdx.x;
  float acc = fb[0];
  #pragma unroll
  for (int i = 0; i < CC; ++i) acc = fmaf(fw[i], x[i*HWSZ + p], acc);
  out[p] = acc;
}

extern "C" void kernel_launch(void* const* d_in, const int* in_sizes, int n_in,
                              void* d_out, int out_size, void* d_ws, size_t ws_size,
                              hipStream_t stream) {
  const float* q       = (const float*)d_in[0];
  const float* proj_w  = (const float*)d_in[1];
  const float* proj_b  = (const float*)d_in[2];
  const float* spec_wr = (const float*)d_in[3];
  const float* spec_wi = (const float*)d_in[4];
  const float* w_w     = (const float*)d_in[5];
  const float* w_b     = (const float*)d_in[6];
  const float* final_w = (const float*)d_in[7];
  const float* final_b = (const float*)d_in[8];
  float* out = (float*)d_out;

  // Workspace (bytes, end-exclusive) — same footprint as R5 (74.25 MB proven):
  //   ctab   [       0,   32768)
  //   stab   [   32768,   65536)
  //   trigBh [   65536,   98304)  32 KiB bf16 (was ctT)
  //   trigBl [   98304,  131072)  32 KiB bf16 (was stT)
  //   X1     [  131072,  4325376) 4 MiB; Thi/Tlo alias it (X1 dead after dfth;
  //          Thi [131072, 2228224), Tlo [2228224, 4325376); dftw rewrites X1 next layer)
  //   Xfp    [ 4325376,  6422528) 2 MiB
  //   Xf     [ 6422528,  6553600) 128 KiB
  //   Yp     [ 6553600,  7077888) 512 KiB
  //   x      [ 7077888, 74186752) 64 MiB
  //   Whi    [74186752, 74219520) 32 KiB bf16 (was wwT)
  //   Wlo    [74219520, 74252288) 32 KiB bf16
  char* ws = (char*)d_ws;
  float*  ctab = (float*) (ws + 0);
  float*  stab = (float*) (ws + 32768);
  unsigned short* trigBh = (unsigned short*)(ws + 65536);
  unsigned short* trigBl = (unsigned short*)(ws + 98304);
  float2* X1   = (float2*)(ws + 131072);
  unsigned short* Thi = (unsigned short*)(ws + 131072);
  unsigned short* Tlo = (unsigned short*)(ws + 2228224);
  float2* Xfp  = (float2*)(ws + 4325376);
  float2* Xf   = (float2*)(ws + 6422528);
  float2* Yp   = (float2*)(ws + 6553600);
  float*  x    = (float*) (ws + 7077888);
  unsigned short* Whi = (unsigned short*)(ws + 74186752);
  unsigned short* Wlo = (unsigned short*)(ws + 74219520);

  k_init<<<96, 256, 0, stream>>>(w_w, ctab, stab, trigBh, trigBl, Whi, Wlo);
  k_lift<<<65536, 256, 0, stream>>>(q, proj_w, proj_b, x);

  for (int d = 0; d < DEPTH; ++d){
    k_dftw<<<2048, 256, 0, stream>>>(x, X1);
    k_dfth<<<dim3(64,16), 256, 0, stream>>>(X1, ctab, stab, Xfp);
    k_redXf<<<64, 256, 0, stream>>>(Xfp, Xf);
    k_contract<<<dim3(64,4), 256, 0, stream>>>(Xf, spec_wr + (size_t)d*1048576,
                                               spec_wi + (size_t)d*1048576, Yp);
    k_idfth<<<2048, 256, 0, stream>>>(Yp, ctab, stab, Thi, Tlo);
    k_combine<<<dim3(8,512), 256, 0, stream>>>(x, Whi + d*4096, Wlo + d*4096,
                                               Thi, Tlo, trigBh, trigBl,
                                               w_b + d*64, x);
  }
  k_final<<<1024, 256, 0, stream>>>(x, final_w, final_b, out);
}

// Round 8
// 414.759 us; speedup vs baseline: 2.4888x; 1.1342x over previous
//
#include <hip/hip_runtime.h>
#include <cmath>

#define CC 64
#define HH 512
#define WWID 512
#define HWSZ (HH*WWID)
#define DEPTH 4

typedef __attribute__((ext_vector_type(8))) short short8;
typedef __attribute__((ext_vector_type(4))) float floatx4;

__device__ inline unsigned short f2bf(float f){
  unsigned int u = __float_as_uint(f);
  u += 0x7FFF + ((u >> 16) & 1);          // round-to-nearest-even
  return (unsigned short)(u >> 16);
}
__device__ inline float bf2f(unsigned short h){
  return __uint_as_float(((unsigned int)h) << 16);
}

// ---------------- init ----------------
// fp32 twiddles (dfth/idfth), bf16-split trig tables in TWO layouts:
//   trigB[w][2n]=cos, [2n+1]=sin      (combine's B rows, k=64..95)
//   trigT[j][w], j=2n→cos, j=2n+1→sin (dftw's B matrix, N=32 x K=512)
// W[d][o][i] split to bf16 hi/lo.
__global__ void k_init(const float* __restrict__ ww,
                       float* __restrict__ ctab, float* __restrict__ stab,
                       unsigned short* __restrict__ trigBh, unsigned short* __restrict__ trigBl,
                       unsigned short* __restrict__ trigTh, unsigned short* __restrict__ trigTl,
                       unsigned short* __restrict__ Whi, unsigned short* __restrict__ Wlo){
  int idx = blockIdx.x*256 + threadIdx.x;
  if (idx < 8192){
    int pos = idx >> 4, k = idx & 15;
    int r = (pos * k) & 511;
    double ang = (2.0 * 3.14159265358979323846 / 512.0) * (double)r;
    float c = (float)cos(ang), s = (float)sin(ang);
    ctab[idx] = c;  stab[idx] = s;
    unsigned short ch = f2bf(c), sh = f2bf(s);
    unsigned short cl = f2bf(c - bf2f(ch)), sl = f2bf(s - bf2f(sh));
    trigBh[pos*32 + 2*k]     = ch;  trigBl[pos*32 + 2*k]     = cl;
    trigBh[pos*32 + 2*k + 1] = sh;  trigBl[pos*32 + 2*k + 1] = sl;
    trigTh[(2*k)*512 + pos]   = ch;  trigTl[(2*k)*512 + pos]   = cl;
    trigTh[(2*k+1)*512 + pos] = sh;  trigTl[(2*k+1)*512 + pos] = sl;
  } else {
    int t = idx - 8192;                   // < 4*64*64, flat [d][o][i]
    float v = ww[t];
    unsigned short h = f2bf(v);
    Whi[t] = h;  Wlo[t] = f2bf(v - bf2f(h));
  }
}

// ---------------- lift: x[c,h,w] = proj_w[c]*q[h,w] + proj_b[c]  (float4) ----------------
__global__ void k_lift(const float4* __restrict__ q, const float* __restrict__ pw,
                       const float* __restrict__ pb, float4* __restrict__ x){
  int idx = blockIdx.x*256 + threadIdx.x;     // < 64*HW/4
  int c = idx >> 16, p = idx & (HWSZ/4 - 1);
  float4 v = q[p];
  float a = pw[c], b = pb[c];
  v.x = fmaf(a, v.x, b); v.y = fmaf(a, v.y, b);
  v.z = fmaf(a, v.z, b); v.w = fmaf(a, v.w, b);
  x[idx] = v;
}

// ---------------- A: DFT along w as split-bf16 MFMA GEMM ----------------
// D[m][j] = sum_w x[row0+m][w] * trigT[j][w];  X1[row][n] = (D[2n], -D[2n+1])
#define APITCH 136   // shorts/row: 272 B, 16B-aligned rows; 68 dwords -> 2-way bank alias (free)
__global__ __launch_bounds__(256) void k_dftw(const float* __restrict__ x,
    const unsigned short* __restrict__ trigTh, const unsigned short* __restrict__ trigTl,
    float* __restrict__ X1f){
  __shared__ unsigned short Ahs[64*APITCH], Als[64*APITCH];
  __shared__ unsigned short Bhs[32*APITCH], Bls[32*APITCH];
  int row0 = blockIdx.x * 64;                 // 64 (c,h) rows per block
  int t = threadIdx.x;
  int g = t >> 6, lm = t & 15, lq = (t >> 4) & 3;

  floatx4 acc[2] = {{0.f,0.f,0.f,0.f},{0.f,0.f,0.f,0.f}};

  for (int kc = 0; kc < 4; ++kc){             // K chunks of 128
    {                                         // stage A: 64 rows x 128 k, fp32 -> split bf16
      int r = t >> 2, q = t & 3;
      const float4* src4 = (const float4*)(x + (size_t)(row0 + r)*512 + kc*128 + q*32);
      unsigned int* dh = (unsigned int*)&Ahs[r*APITCH + q*32];
      unsigned int* dl = (unsigned int*)&Als[r*APITCH + q*32];
      #pragma unroll
      for (int u = 0; u < 8; ++u){
        float4 v = src4[u];
        unsigned short h0 = f2bf(v.x), h1 = f2bf(v.y), h2 = f2bf(v.z), h3 = f2bf(v.w);
        dh[u*2]   = (unsigned)h0 | ((unsigned)h1 << 16);
        dh[u*2+1] = (unsigned)h2 | ((unsigned)h3 << 16);
        unsigned short g0 = f2bf(v.x - bf2f(h0)), g1 = f2bf(v.y - bf2f(h1));
        unsigned short g2 = f2bf(v.z - bf2f(h2)), g3 = f2bf(v.w - bf2f(h3));
        dl[u*2]   = (unsigned)g0 | ((unsigned)g1 << 16);
        dl[u*2+1] = (unsigned)g2 | ((unsigned)g3 << 16);
      }
    }
    {                                         // stage B: 32 rows x 128 k (bf16 copy)
      int j = t >> 3, q = t & 7;
      const unsigned int* sh = (const unsigned int*)trigTh + j*256 + kc*64 + q*8;
      const unsigned int* sl = (const unsigned int*)trigTl + j*256 + kc*64 + q*8;
      unsigned int* dh = (unsigned int*)&Bhs[j*APITCH + q*16];
      unsigned int* dl = (unsigned int*)&Bls[j*APITCH + q*16];
      #pragma unroll
      for (int u = 0; u < 8; ++u){ dh[u] = sh[u]; dl[u] = sl[u]; }
    }
    __syncthreads();
    #pragma unroll
    for (int ks = 0; ks < 4; ++ks){
      short8 ah = *(const short8*)&Ahs[(g*16 + lm)*APITCH + ks*32 + lq*8];
      short8 al = *(const short8*)&Als[(g*16 + lm)*APITCH + ks*32 + lq*8];
      #pragma unroll
      for (int nt = 0; nt < 2; ++nt){
        short8 bh = *(const short8*)&Bhs[(nt*16 + lm)*APITCH + ks*32 + lq*8];
        short8 bl = *(const short8*)&Bls[(nt*16 + lm)*APITCH + ks*32 + lq*8];
        acc[nt] = __builtin_amdgcn_mfma_f32_16x16x32_bf16(ah, bh, acc[nt], 0, 0, 0);
        acc[nt] = __builtin_amdgcn_mfma_f32_16x16x32_bf16(ah, bl, acc[nt], 0, 0, 0);
        acc[nt] = __builtin_amdgcn_mfma_f32_16x16x32_bf16(al, bh, acc[nt], 0, 0, 0);
      }
    }
    __syncthreads();
  }
  // D layout: row m = g*16 + lq*4 + rg, col j = nt*16 + lm. X1f[row*32 + j], odd j negated.
  #pragma unroll
  for (int nt = 0; nt < 2; ++nt){
    int j = nt*16 + lm;
    float sgn = (j & 1) ? -1.f : 1.f;
    #pragma unroll
    for (int rg = 0; rg < 4; ++rg){
      int m = g*16 + lq*4 + rg;
      X1f[(size_t)(row0 + m)*32 + j] = sgn * acc[nt][rg];
    }
  }
}

// ---------------- B1: partial DFT along h (16 chunks of 32): Xfp[ch][i][mn] ----------------
__global__ void k_dfth(const float2* __restrict__ X1, const float* __restrict__ ct,
                       const float* __restrict__ st, float2* __restrict__ Xfp){
  int i = blockIdx.x, ch = blockIdx.y;
  int m = threadIdx.x >> 4, n = threadIdx.x & 15;
  float ar = 0.f, ai = 0.f;
  int h0 = ch * 32;
  #pragma unroll 8
  for (int hh = 0; hh < 32; ++hh){
    int h = h0 + hh;
    float2 v = X1[(i*512 + h)*16 + n];
    float c = ct[h*16 + m], s = st[h*16 + m];
    ar += v.x*c + v.y*s;
    ai += v.y*c - v.x*s;
  }
  Xfp[(ch*64 + i)*256 + threadIdx.x] = make_float2(ar, ai);
}

// ---------------- B1b: reduce h-chunk partials ----------------
__global__ void k_redXf(const float2* __restrict__ Xfp, float2* __restrict__ Xf){
  int i = blockIdx.x, mn = threadIdx.x;
  float ar = 0.f, ai = 0.f;
  #pragma unroll
  for (int ch = 0; ch < 16; ++ch){
    float2 v = Xfp[(ch*64 + i)*256 + mn];
    ar += v.x; ai += v.y;
  }
  Xf[i*256 + mn] = make_float2(ar, ai);
}

// ---------------- B2: mode contraction, i-chunked, mn-split (64-thread blocks) ----------------
__global__ void k_contract(const float2* __restrict__ Xf,
                           const float* __restrict__ wr, const float* __restrict__ wi,
                           float2* __restrict__ Yp){
  int o = blockIdx.x, ic = blockIdx.y;
  int mn = blockIdx.z*64 + threadIdx.x;
  float ar = 0.f, ai = 0.f;
  int i0 = ic * 16;
  #pragma unroll
  for (int ii = 0; ii < 16; ++ii){
    int i = i0 + ii;
    float2 xf = Xf[i*256 + mn];
    float wrv = wr[(i*64 + o)*256 + mn];
    float wiv = wi[(i*64 + o)*256 + mn];
    ar += xf.x*wrv - xf.y*wiv;
    ai += xf.x*wiv + xf.y*wrv;
  }
  const float sc = 1.f/262144.f;
  Yp[(ic*64 + o)*256 + mn] = make_float2(ar*sc, ai*sc);
}

// ---------------- B3: inverse DFT along h -> T, split bf16 hi/lo, sign-folded ----------------
__global__ void k_idfth(const float2* __restrict__ Yp, const float* __restrict__ ct,
                        const float* __restrict__ st,
                        unsigned short* __restrict__ Thi, unsigned short* __restrict__ Tlo){
  int idx = blockIdx.x*256 + threadIdx.x;     // (h*64+o)*16+n
  int n = idx & 15, o = (idx >> 4) & 63, h = idx >> 10;
  float ar = 0.f, ai = 0.f;
  #pragma unroll
  for (int m = 0; m < 16; ++m){
    float yr = 0.f, yi = 0.f;
    #pragma unroll
    for (int jc = 0; jc < 4; ++jc){
      float2 y = Yp[((jc<<6) + o)*256 + (m<<4) + n];
      yr += y.x; yi += y.y;
    }
    float c = ct[h*16 + m], s = st[h*16 + m];
    ar += yr*c - yi*s;
    ai += yr*s + yi*c;
  }
  float tr = ar, ts = -ai;
  unsigned short rh = f2bf(tr), sh = f2bf(ts);
  size_t base = ((size_t)(h*64 + o))*32 + 2*n;
  Thi[base] = rh;  Thi[base+1] = sh;
  Tlo[base] = f2bf(tr - bf2f(rh));  Tlo[base+1] = f2bf(ts - bf2f(sh));
}

// ---------------- C: combine GEMM (K=96: conv 64 + spectral 32), split-bf16 3-pass ----------------
#define PITCH 104   // 208 B rows: 16B-aligned, 2-way bank alias (free)
__global__ __launch_bounds__(256) void k_combine(
    const float* __restrict__ x,
    const unsigned short* __restrict__ Whid, const unsigned short* __restrict__ Wlod,
    const unsigned short* __restrict__ Thi,  const unsigned short* __restrict__ Tlo,
    const unsigned short* __restrict__ trigBh, const unsigned short* __restrict__ trigBl,
    const float* __restrict__ wb, float* __restrict__ xo)
{
  __shared__ unsigned short Ah[64*PITCH], Al[64*PITCH];   // rows o, k 0..95
  __shared__ unsigned short Bh[64*PITCH], Bl[64*PITCH];   // rows w(pixel), k 0..95
  int h  = blockIdx.y;
  int w0 = blockIdx.x * 64;
  int t  = threadIdx.x;

  {   // B x-part: coalesced reads, packed b32 LDS writes
    int wl = t & 63, ig = t >> 6;
    const float* xb = x + (size_t)h*512 + w0 + wl;
    #pragma unroll
    for (int ii = 0; ii < 16; ii += 2){
      int i0 = ig*16 + ii;
      float v0 = xb[(size_t)i0*HWSZ];
      float v1 = xb[(size_t)(i0+1)*HWSZ];
      unsigned short h0 = f2bf(v0), h1 = f2bf(v1);
      unsigned short g0 = f2bf(v0 - bf2f(h0)), g1 = f2bf(v1 - bf2f(h1));
      *(unsigned int*)&Bh[wl*PITCH + i0] = (unsigned int)h0 | ((unsigned int)h1 << 16);
      *(unsigned int*)&Bl[wl*PITCH + i0] = (unsigned int)g0 | ((unsigned int)g1 << 16);
    }
  }
  {   // B trig-part: rows w, k=64..95
    int row = t >> 2, qq = t & 3;
    const unsigned int* sh = (const unsigned int*)trigBh + (size_t)(w0+row)*16 + qq*4;
    const unsigned int* sl = (const unsigned int*)trigBl + (size_t)(w0+row)*16 + qq*4;
    unsigned int* dh = (unsigned int*)&Bh[row*PITCH + 64] + qq*4;
    unsigned int* dl = (unsigned int*)&Bl[row*PITCH + 64] + qq*4;
    #pragma unroll
    for (int u = 0; u < 4; ++u){ dh[u] = sh[u]; dl[u] = sl[u]; }
  }
  {   // A W-part: rows o, k=0..63
    int o = t >> 2, q8 = t & 3;
    const unsigned int* sh = (const unsigned int*)Whid + o*32 + q8*8;
    const unsigned int* sl = (const unsigned int*)Wlod + o*32 + q8*8;
    unsigned int* dh = (unsigned int*)&Ah[o*PITCH] + q8*8;
    unsigned int* dl = (unsigned int*)&Al[o*PITCH] + q8*8;
    #pragma unroll
    for (int u = 0; u < 8; ++u){ dh[u] = sh[u]; dl[u] = sl[u]; }
  }
  {   // A T-part: rows o, k=64..95
    int o = t >> 2, q4 = t & 3;
    const unsigned int* sh = (const unsigned int*)Thi + (size_t)h*1024 + o*16 + q4*4;
    const unsigned int* sl = (const unsigned int*)Tlo + (size_t)h*1024 + o*16 + q4*4;
    unsigned int* dh = (unsigned int*)&Ah[o*PITCH + 64] + q4*4;
    unsigned int* dl = (unsigned int*)&Al[o*PITCH + 64] + q4*4;
    #pragma unroll
    for (int u = 0; u < 4; ++u){ dh[u] = sh[u]; dl[u] = sl[u]; }
  }
  __syncthreads();

  int g  = t >> 6;          // wave -> m-tile (o-rows g*16..+15)
  int lm = t & 15;
  int lq = (t >> 4) & 3;

  floatx4 acc[4] = {{0.f,0.f,0.f,0.f},{0.f,0.f,0.f,0.f},{0.f,0.f,0.f,0.f},{0.f,0.f,0.f,0.f}};

  // ks-outer: Ah/Al fragments loaded once, shared across the 3 split passes (30 vs 45 b128/wave)
  #pragma unroll
  for (int ks = 0; ks < 3; ++ks){
    short8 af = *(const short8*)&Ah[(g*16 + lm)*PITCH + ks*32 + lq*8];
    short8 al = *(const short8*)&Al[(g*16 + lm)*PITCH + ks*32 + lq*8];
    #pragma unroll
    for (int nt = 0; nt < 4; ++nt){
      short8 bf = *(const short8*)&Bh[(nt*16 + lm)*PITCH + ks*32 + lq*8];
      short8 bl = *(const short8*)&Bl[(nt*16 + lm)*PITCH + ks*32 + lq*8];
      acc[nt] = __builtin_amdgcn_mfma_f32_16x16x32_bf16(af, bf, acc[nt], 0, 0, 0);
      acc[nt] = __builtin_amdgcn_mfma_f32_16x16x32_bf16(af, bl, acc[nt], 0, 0, 0);
      acc[nt] = __builtin_amdgcn_mfma_f32_16x16x32_bf16(al, bf, acc[nt], 0, 0, 0);
    }
  }

  // epilogue: bias + tanh-gelu + store (D: row=o=g*16+lq*4+rg, col=w=nt*16+lm)
  #pragma unroll
  for (int nt = 0; nt < 4; ++nt){
    int w = w0 + nt*16 + lm;
    #pragma unroll
    for (int rg = 0; rg < 4; ++rg){
      int o = g*16 + lq*4 + rg;
      float u = acc[nt][rg] + wb[o];
      float z = 0.7978845608028654f * fmaf(0.044715f, u*u*u, u);
      float e = __expf(2.f*z);
      float gl = u - __fdividef(u, e + 1.f);
      xo[(size_t)o*HWSZ + (size_t)h*512 + w] = gl;
    }
  }
}

// ---------------- final projection (float4) ----------------
__global__ void k_final(const float* __restrict__ x, const float* __restrict__ fw,
                        const float* __restrict__ fb, float4* __restrict__ out){
  int p4 = blockIdx.x*256 + threadIdx.x;      // < HW/4 = 65536
  float b = fb[0];
  float4 acc = make_float4(b, b, b, b);
  #pragma unroll
  for (int i = 0; i < CC; ++i){
    float4 v = *(const float4*)(x + (size_t)i*HWSZ + (size_t)p4*4);
    float wv = fw[i];
    acc.x = fmaf(wv, v.x, acc.x); acc.y = fmaf(wv, v.y, acc.y);
    acc.z = fmaf(wv, v.z, acc.z); acc.w = fmaf(wv, v.w, acc.w);
  }
  out[p4] = acc;
}

extern "C" void kernel_launch(void* const* d_in, const int* in_sizes, int n_in,
                              void* d_out, int out_size, void* d_ws, size_t ws_size,
                              hipStream_t stream) {
  const float* q       = (const float*)d_in[0];
  const float* proj_w  = (const float*)d_in[1];
  const float* proj_b  = (const float*)d_in[2];
  const float* spec_wr = (const float*)d_in[3];
  const float* spec_wi = (const float*)d_in[4];
  const float* w_w     = (const float*)d_in[5];
  const float* w_b     = (const float*)d_in[6];
  const float* final_w = (const float*)d_in[7];
  const float* final_b = (const float*)d_in[8];
  float* out = (float*)d_out;

  // Workspace (bytes, end-exclusive):
  //   ctab   [       0,   32768)
  //   stab   [   32768,   65536)
  //   trigBh [   65536,   98304)   trigBl [   98304,  131072)
  //   X1     [  131072,  4325376)  4 MiB; Thi [131072,2228224) Tlo [2228224,4325376) alias
  //   Xfp    [ 4325376,  6422528)  2 MiB
  //   Xf     [ 6422528,  6553600)  128 KiB
  //   Yp     [ 6553600,  7077888)  512 KiB
  //   x      [ 7077888, 74186752)  64 MiB
  //   Whi    [74186752, 74219520)  Wlo [74219520, 74252288)
  //   trigTh [74252288, 74285056)  trigTl [74285056, 74317824)   total ~74.3 MiB
  char* ws = (char*)d_ws;
  float*  ctab = (float*) (ws + 0);
  float*  stab = (float*) (ws + 32768);
  unsigned short* trigBh = (unsigned short*)(ws + 65536);
  unsigned short* trigBl = (unsigned short*)(ws + 98304);
  float2* X1   = (float2*)(ws + 131072);
  unsigned short* Thi = (unsigned short*)(ws + 131072);
  unsigned short* Tlo = (unsigned short*)(ws + 2228224);
  float2* Xfp  = (float2*)(ws + 4325376);
  float2* Xf   = (float2*)(ws + 6422528);
  float2* Yp   = (float2*)(ws + 6553600);
  float*  x    = (float*) (ws + 7077888);
  unsigned short* Whi = (unsigned short*)(ws + 74186752);
  unsigned short* Wlo = (unsigned short*)(ws + 74219520);
  unsigned short* trigTh = (unsigned short*)(ws + 74252288);
  unsigned short* trigTl = (unsigned short*)(ws + 74285056);

  k_init<<<96, 256, 0, stream>>>(w_w, ctab, stab, trigBh, trigBl, trigTh, trigTl, Whi, Wlo);
  k_lift<<<16384, 256, 0, stream>>>((const float4*)q, proj_w, proj_b, (float4*)x);

  for (int d = 0; d < DEPTH; ++d){
    k_dftw<<<512, 256, 0, stream>>>(x, trigTh, trigTl, (float*)X1);
    k_dfth<<<dim3(64,16), 256, 0, stream>>>(X1, ctab, stab, Xfp);
    k_redXf<<<64, 256, 0, stream>>>(Xfp, Xf);
    k_contract<<<dim3(64,4,4), 64, 0, stream>>>(Xf, spec_wr + (size_t)d*1048576,
                                                spec_wi + (size_t)d*1048576, Yp);
    k_idfth<<<2048, 256, 0, stream>>>(Yp, ctab, stab, Thi, Tlo);
    k_combine<<<dim3(8,512), 256, 0, stream>>>(x, Whi + d*4096, Wlo + d*4096,
                                               Thi, Tlo, trigBh, trigBl,
                                               w_b + d*64, x);
  }
  // 65536 float4s / 256 threads = 256 blocks (R7 bug: 1024 blocks -> 3 MB OOB write past d_out)
  k_final<<<256, 256, 0, stream>>>(x, final_w, final_b, (float4*)out);
}